// Round 13
// baseline (138.823 us; speedup 1.0000x reference)
//
#include <hip/hip_runtime.h>
#include <stdint.h>

#define N_REAL 500
#define NPAD   512
#define K_IN   3072
#define NBATCH 8192
#define NOUT   10
#define RADIUS 20.0f
#define VOLF   100.0f

typedef __attribute__((ext_vector_type(8))) __bf16 bf16x8;
typedef __attribute__((ext_vector_type(4))) float  f32x4;
typedef __attribute__((ext_vector_type(4))) unsigned short us4;

__device__ __forceinline__ unsigned short f2bf(float f) {
    unsigned int u = __float_as_uint(f);
    u += 0x7FFFu + ((u >> 16) & 1u);           // round-to-nearest-even
    return (unsigned short)(u >> 16);
}
__device__ __forceinline__ float bf2f(unsigned short h) {
    return __uint_as_float(((unsigned int)h) << 16);
}
// HW packed f32->bf16 (RNE), 2 insts per float4
__device__ __forceinline__ uint2 cvt_pk4(float4 v) {
    uint2 r;
    asm("v_cvt_pk_bf16_f32 %0, %1, %2" : "=v"(r.x) : "v"(v.x), "v"(v.y));
    asm("v_cvt_pk_bf16_f32 %0, %1, %2" : "=v"(r.y) : "v"(v.z), "v"(v.w));
    return r;
}

#define GLOBAL_AS __attribute__((address_space(1)))
#define LDS_AS    __attribute__((address_space(3)))
__device__ __forceinline__ void glds16(const void* g, void* l) {
    __builtin_amdgcn_global_load_lds((const GLOBAL_AS void*)g, (LDS_AS void*)l, 16, 0, 0);
}

// ---------------- prep1 ----------------
__global__ void prep1(const float* __restrict__ positions,
                      const float* __restrict__ features,
                      const float* __restrict__ out_w,
                      const float* __restrict__ biases,
                      float* __restrict__ feat_norm,   // [512][64]
                      float* __restrict__ pos_c,       // [512][4]
                      float* __restrict__ inw,         // [512]
                      float* __restrict__ biasp,       // [512]
                      float* __restrict__ wout)        // [512][10]
{
    int n = threadIdx.x;  // 512 threads, 1 block
    float e_in = 0.f, e_out = 0.f;
    float px = 0.f, py = 0.f, pz = 0.f;
    if (n < N_REAL) {
        px = fminf(fmaxf(positions[n*3+0], 0.1f), VOLF - 0.1f);
        py = fminf(fmaxf(positions[n*3+1], 0.1f), VOLF - 0.1f);
        pz = fminf(fmaxf(positions[n*3+2], 0.1f), VOLF - 0.1f);
        float xn = px / VOLF;
        e_in  = expf(-2.f * xn);
        e_out = expf(2.f * (xn - 1.f));
        float ss = 0.f;
        for (int f = 0; f < 64; ++f) { float v = features[n*64+f]; ss += v*v; }
        float nm = fmaxf(sqrtf(ss), 1e-6f);
        for (int f = 0; f < 64; ++f) feat_norm[n*64+f] = features[n*64+f] / nm;
    } else {
        for (int f = 0; f < 64; ++f) feat_norm[n*64+f] = 0.f;
    }
    pos_c[n*4+0] = px; pos_c[n*4+1] = py; pos_c[n*4+2] = pz; pos_c[n*4+3] = 0.f;

    __shared__ float s_in[512], s_out[512];
    s_in[n] = e_in; s_out[n] = e_out;
    __syncthreads();
    for (int s = 256; s > 0; s >>= 1) {
        if (n < s) { s_in[n] += s_in[n+s]; s_out[n] += s_out[n+s]; }
        __syncthreads();
    }
    float sum_in  = s_in[0]  + 1e-6f;
    float sum_out = s_out[0] + 1e-6f;

    inw[n]   = (n < N_REAL) ? (e_in / sum_in) : 0.f;
    biasp[n] = (n < N_REAL) ? biases[n] : 0.f;
    float wo = (n < N_REAL) ? (e_out / sum_out) : 0.f;
    for (int o = 0; o < NOUT; ++o)
        wout[n*NOUT + o] = (n < N_REAL) ? out_w[n*NOUT + o] * wo : 0.f;
}

// ---------------- prep2 ----------------
__global__ void prep2(const float* __restrict__ pos_c,
                      const float* __restrict__ feat_norm,
                      unsigned short* __restrict__ conn_w)   // [512][512] bf16
{
    int i = blockIdx.x;   // 512
    int t = threadIdx.x;  // 128
    __shared__ float fi[64];
    __shared__ float spos[4];
    __shared__ float red[128];
    if (t < 64) fi[t] = feat_norm[i*64 + t];
    if (t < 4)  spos[t] = pos_c[i*4 + t];
    __syncthreads();

    float w[4];
    float part = 0.f;
    for (int jj = 0; jj < 4; ++jj) {
        int j = t + jj*128;
        float val = 0.f;
        if (i < N_REAL && j < N_REAL) {
            float dx = spos[0] - pos_c[j*4+0];
            float dy = spos[1] - pos_c[j*4+1];
            float dz = spos[2] - pos_c[j*4+2];
            float sq = dx*dx + dy*dy + dz*dz;
            if (sq > 0.f) {
                float dist = sqrtf(sq);
                if (dist < RADIUS) {
                    float att = expf(-dist / RADIUS);
                    float sim = 0.f;
                    const float4* fj = (const float4*)(feat_norm + j*64);
                    const float4* fi4 = (const float4*)fi;
                    #pragma unroll
                    for (int f = 0; f < 16; ++f) {
                        float4 a = fi4[f]; float4 b = fj[f];
                        sim += a.x*b.x + a.y*b.y + a.z*b.z + a.w*b.w;
                    }
                    sim = fminf(fmaxf(sim, -1.f), 1.f);
                    val = att * (0.5f + 0.5f*sim);
                }
            }
        }
        w[jj] = val; part += val;
    }
    red[t] = part;
    __syncthreads();
    for (int s = 64; s > 0; s >>= 1) {
        if (t < s) red[t] += red[t+s];
        __syncthreads();
    }
    float inv = 1.f / (red[0] + 1e-6f);
    for (int jj = 0; jj < 4; ++jj)
        conn_w[(long)i*NPAD + t + jj*128] = f2bf(w[jj] * inv);
}

// ---------------- cast/pad f32 -> bf16 ----------------
__global__ void cast_pad(const float* __restrict__ src, unsigned short* __restrict__ dst,
                         long total_q, long src_q)
{
    long i = (long)blockIdx.x * blockDim.x + threadIdx.x;
    long stride = (long)gridDim.x * blockDim.x;
    for (; i < total_q; i += stride) {
        us4 o;
        if (i < src_q) {
            float4 v = ((const float4*)src)[i];
            o[0] = f2bf(v.x); o[1] = f2bf(v.y); o[2] = f2bf(v.z); o[3] = f2bf(v.w);
        } else {
            o[0] = 0; o[1] = 0; o[2] = 0; o[3] = 0;
        }
        ((us4*)dst)[i] = o;
    }
}

// gemm1 map: 2048 blocks = 8 XCD x (16 m-panels x 4 n x 4 ks).
// 4 n-blocks + 4 ks of one m-panel co-located per XCD -> A-panel L2/L3 reuse.
__device__ __forceinline__ void block_map_g1(int b, int& m0, int& n0, int& ks) {
    int xcd = b & 7, loc = b >> 3;          // loc 0..255
    m0 = (xcd*16 + (loc >> 4)) * 64;
    int rest = loc & 15;
    n0 = (rest & 3) * 128;
    ks = rest >> 2;
}
// 512-block map (gemm2): 128 m-panels x 4 n-quarters.
__device__ __forceinline__ void block_map_g2(int b, int& m0, int& n0) {
    int xcd = b & 7, loc = b >> 3;          // loc 0..63
    m0 = (xcd*16 + (loc >> 2)) * 64;
    n0 = (loc & 3) * 128;
}

// ======== GEMM1 split-K4: tile 64x128, BK=64, strict single-buffer loop. ========
// r12 kernel with 4-way K-split: grid 2048 -> 8 blocks/CU assigned, 6 resident
// (LDS 24 KB x 6 = 144 KB). Per-iter chain unchanged (4 f4-loads + 4 glds16).
__global__ __launch_bounds__(256, 6)
void gemm1s(const float* __restrict__ X,            // [8192][3072] f32
            const unsigned short* __restrict__ B,   // [512][3072] bf16
            float* __restrict__ Pf)                 // [4][8192][512] f32 partials
{
    __shared__ unsigned short As[64*64];    //  8 KiB, swizzled
    __shared__ unsigned short Bs[128*64];   // 16 KiB, swizzled

    const int tid  = threadIdx.x;
    const int lane = tid & 63;
    const int wave = tid >> 6;
    int m0, n0, ks; block_map_g1(blockIdx.x, m0, n0, ks);
    const int kbase = ks * (K_IN/4);          // 0,768,1536,2304
    const int wm = (wave >> 1) * 32;
    const int wn = (wave & 1) * 64;

    f32x4 acc[2][4];
    #pragma unroll
    for (int i = 0; i < 2; ++i)
        #pragma unroll
        for (int j = 0; j < 4; ++j)
            acc[i][j] = (f32x4){0.f,0.f,0.f,0.f};

    // A reg-staging: 64 rows x 16 float4 = 1024 f4, 4 per thread
    const float4* gA[4]; int lAo[4];
    #pragma unroll
    for (int s = 0; s < 4; ++s) {
        int f = tid + s*256;
        int row = f >> 4, c4 = f & 15;
        gA[s] = (const float4*)(X + (long)(m0 + row) * K_IN + kbase) + c4;
        lAo[s] = row*128 + ((c4*8) ^ ((row & 7) << 4));
    }
    // B: 16 KB = 4 glds16/thread, pre-swizzled global source
    const char* gB[4]; char* lB[4];
    #pragma unroll
    for (int s = 0; s < 4; ++s) {
        int o = tid*16 + s*4096;
        int row = o >> 7, d = o & 127;
        gB[s] = (const char*)B + (long)(n0 + row) * (K_IN*2) + kbase*2 + (d ^ ((row & 7) << 4));
        lB[s] = (char*)Bs + o;
    }

    for (int t = 0; t < 12; ++t) {
        __syncthreads();
        #pragma unroll
        for (int s = 0; s < 4; ++s) { glds16(gB[s], lB[s]); gB[s] += 128; }
        float4 v[4];
        #pragma unroll
        for (int s = 0; s < 4; ++s) { v[s] = gA[s][0]; gA[s] += 16; }
        #pragma unroll
        for (int s = 0; s < 4; ++s)
            *(uint2*)((char*)As + lAo[s]) = cvt_pk4(v[s]);
        asm volatile("s_waitcnt vmcnt(0) lgkmcnt(0)" ::: "memory");
        __syncthreads();

        #pragma unroll
        for (int kk = 0; kk < 2; ++kk) {
            const int cb = kk*64 + (lane >> 4) * 16;
            bf16x8 afr[2], bfr[4];
            #pragma unroll
            for (int i = 0; i < 2; ++i) {
                int r = wm + i*16 + (lane & 15);
                afr[i] = *(const bf16x8*)((const char*)As + r*128 + (cb ^ ((r & 7) << 4)));
            }
            #pragma unroll
            for (int j = 0; j < 4; ++j) {
                int r = wn + j*16 + (lane & 15);
                bfr[j] = *(const bf16x8*)((const char*)Bs + r*128 + (cb ^ ((r & 7) << 4)));
            }
            #pragma unroll
            for (int i = 0; i < 2; ++i)
                #pragma unroll
                for (int j = 0; j < 4; ++j)
                    acc[i][j] = __builtin_amdgcn_mfma_f32_16x16x32_bf16(afr[i], bfr[j], acc[i][j], 0, 0, 0);
        }
    }

    // raw f32 partial store
    float* P = Pf + (long)ks * (NBATCH * (long)NPAD);
    const int mbase = m0 + wm + (lane >> 4) * 4;
    const int nbase = n0 + wn + (lane & 15);
    #pragma unroll
    for (int j = 0; j < 4; ++j) {
        const int n = nbase + j*16;
        #pragma unroll
        for (int i = 0; i < 2; ++i)
            #pragma unroll
            for (int r = 0; r < 4; ++r) {
                const long m = mbase + i*16 + r;
                P[m*NPAD + n] = acc[i][j][r];
            }
    }
}

// ---- reduce 4 partials (fixed order) + input-gate epilogue -> act bf16 ----
__global__ __launch_bounds__(256)
void reduce_ep(const float* __restrict__ Pf,       // [4][8192][512] f32
               const float* __restrict__ inw,
               const float* __restrict__ biasp,
               unsigned short* __restrict__ act)   // [8192][512] bf16
{
    const long TOTQ = (long)NBATCH * NPAD / 4;     // 1,048,576 float4
    long i = (long)blockIdx.x * blockDim.x + threadIdx.x;
    long stride = (long)gridDim.x * blockDim.x;
    for (; i < TOTQ; i += stride) {
        float4 a = ((const float4*)Pf)[i];
        float4 b = ((const float4*)Pf)[i + TOTQ];
        float4 c = ((const float4*)Pf)[i + 2*TOTQ];
        float4 d = ((const float4*)Pf)[i + 3*TOTQ];
        int nq = (int)(i & 127);                   // (n/4) index
        float4 w  = ((const float4*)inw)[nq];
        float4 bi = ((const float4*)biasp)[nq];
        us4 o;
        o[0] = f2bf((((a.x + b.x) + c.x) + d.x) * w.x + bi.x);
        o[1] = f2bf((((a.y + b.y) + c.y) + d.y) * w.y + bi.y);
        o[2] = f2bf((((a.z + b.z) + c.z) + d.z) * w.z + bi.z);
        o[3] = f2bf((((a.w + b.w) + c.w) + d.w) * w.w + bi.w);
        ((us4*)act)[i] = o;
    }
}

// ======== GEMM2 (r8/r10-proven): BM=64, BN=128, BK=64, 3-buffer ring, depth-2. ========
__global__ __launch_bounds__(256, 4)
void gemm2_pipe(const unsigned short* __restrict__ A,      // act [8192][512] bf16
                const unsigned short* __restrict__ B,      // connw [512][512] bf16
                unsigned short* __restrict__ Cbf,          // [8192][512] bf16
                const unsigned short* __restrict__ actOld) // == A
{
    constexpr int ABUF = 8192;    // 64 x 64 bf16
    constexpr int BBUF = 16384;   // 128 x 64 bf16
    __shared__ __align__(16) char lds[3*(ABUF+BBUF)];  // 72 KB
    char* const Abase = lds;
    char* const Bbase = lds + 3*ABUF;

    const int tid  = threadIdx.x;
    const int lane = tid & 63;
    const int wave = tid >> 6;
    int m0, n0; block_map_g2(blockIdx.x, m0, n0);
    const int wm = (wave >> 1) * 32;
    const int wn = (wave & 1) * 64;

    f32x4 acc[2][4];
    #pragma unroll
    for (int i = 0; i < 2; ++i)
        #pragma unroll
        for (int j = 0; j < 4; ++j)
            acc[i][j] = (f32x4){0.f,0.f,0.f,0.f};

    const char* gB[4]; int lBo[4];
    #pragma unroll
    for (int s = 0; s < 4; ++s) {
        int o = tid*16 + s*4096;
        int row = o >> 7, d = o & 127;
        gB[s] = (const char*)B + (long)(n0 + row) * (NPAD*2) + (d ^ ((row & 7) << 4));
        lBo[s] = o;
    }
    const char* gA1[2]; int lAo1[2];
    #pragma unroll
    for (int s = 0; s < 2; ++s) {
        int o = tid*16 + s*4096;
        int row = o >> 7, d = o & 127;
        gA1[s] = (const char*)A + (long)(m0 + row) * (NPAD*2) + (d ^ ((row & 7) << 4));
        lAo1[s] = o;
    }

    const int NT = NPAD >> 6;   // 8

    // prologue: tiles 0,1 in flight
    #pragma unroll
    for (int s = 0; s < 2; ++s) { glds16(gA1[s], Abase + 0*ABUF + lAo1[s]); gA1[s] += 128; }
    #pragma unroll
    for (int s = 0; s < 4; ++s) { glds16(gB[s], Bbase + 0*BBUF + lBo[s]); gB[s] += 128; }
    #pragma unroll
    for (int s = 0; s < 2; ++s) { glds16(gA1[s], Abase + 1*ABUF + lAo1[s]); gA1[s] += 128; }
    #pragma unroll
    for (int s = 0; s < 4; ++s) { glds16(gB[s], Bbase + 1*BBUF + lBo[s]); gB[s] += 128; }

    int cur = 0;
    for (int t = 0; t < NT; ++t) {
        int fb = cur + 2; if (fb >= 3) fb -= 3;
        const bool more2 = (t + 2 < NT);
        const bool more1 = (t + 1 < NT);
        if (more2) {
            #pragma unroll
            for (int s = 0; s < 2; ++s) { glds16(gA1[s], Abase + fb*ABUF + lAo1[s]); gA1[s] += 128; }
            #pragma unroll
            for (int s = 0; s < 4; ++s) { glds16(gB[s], Bbase + fb*BBUF + lBo[s]); gB[s] += 128; }
            asm volatile("s_waitcnt vmcnt(12)" ::: "memory");
        } else if (more1) {
            asm volatile("s_waitcnt vmcnt(6)" ::: "memory");
        } else {
            asm volatile("s_waitcnt vmcnt(0)" ::: "memory");
        }
        __builtin_amdgcn_s_barrier();

        const char* Ab = Abase + cur*ABUF;
        const char* Bb = Bbase + cur*BBUF;
        #pragma unroll
        for (int kk = 0; kk < 2; ++kk) {
            const int cb = kk*64 + (lane >> 4) * 16;
            bf16x8 afr[2], bfr[4];
            #pragma unroll
            for (int i = 0; i < 2; ++i) {
                int r = wm + i*16 + (lane & 15);
                afr[i] = *(const bf16x8*)(Ab + r*128 + (cb ^ ((r & 7) << 4)));
            }
            #pragma unroll
            for (int j = 0; j < 4; ++j) {
                int r = wn + j*16 + (lane & 15);
                bfr[j] = *(const bf16x8*)(Bb + r*128 + (cb ^ ((r & 7) << 4)));
            }
            #pragma unroll
            for (int i = 0; i < 2; ++i)
                #pragma unroll
                for (int j = 0; j < 4; ++j)
                    acc[i][j] = __builtin_amdgcn_mfma_f32_16x16x32_bf16(afr[i], bfr[j], acc[i][j], 0, 0, 0);
        }
        __builtin_amdgcn_s_barrier();
        cur = (cur == 2) ? 0 : cur + 1;
    }

    const int mbase = m0 + wm + (lane >> 4) * 4;
    const int nbase = n0 + wn + (lane & 15);
    #pragma unroll
    for (int j = 0; j < 4; ++j) {
        const int n = nbase + j*16;
        #pragma unroll
        for (int i = 0; i < 2; ++i)
            #pragma unroll
            for (int r = 0; r < 4; ++r) {
                const long m = mbase + i*16 + r;
                float old = bf2f(actOld[m*NPAD + n]);
                float vv = fminf(fmaxf(old + 0.5f * acc[i][j][r], 0.f), 50.f);
                Cbf[m*NPAD + n] = f2bf(vv);
            }
    }
}

// ---------------- final projection: out[8192][10] = act @ wout ----------------
__global__ __launch_bounds__(256)
void out_gemm(const unsigned short* __restrict__ act,  // [8192][512] bf16
              const float* __restrict__ wout,          // [512][10]
              float* __restrict__ out)                 // [8192][10]
{
    __shared__ float sw[NPAD * NOUT];
    const int tid = threadIdx.x;
    for (int i = tid; i < NPAD*NOUT; i += 256) sw[i] = wout[i];
    __syncthreads();

    const int lane = tid & 63;
    const int wv   = tid >> 6;
    const int row  = blockIdx.x * 4 + wv;

    const unsigned short* ap = act + (long)row * NPAD + lane * 8;
    us4 v0 = *(const us4*)(ap);
    us4 v1 = *(const us4*)(ap + 4);

    float p[NOUT];
    #pragma unroll
    for (int o = 0; o < NOUT; ++o) p[o] = 0.f;

    const int nb = lane * 8;
    #pragma unroll
    for (int e = 0; e < 8; ++e) {
        float a = bf2f(e < 4 ? v0[e] : v1[e-4]);
        const float* wr = &sw[(nb + e) * NOUT];
        #pragma unroll
        for (int o = 0; o < NOUT; ++o) p[o] += a * wr[o];
    }
    #pragma unroll
    for (int o = 0; o < NOUT; ++o) {
        float s = p[o];
        for (int d = 32; d > 0; d >>= 1) s += __shfl_down(s, d);
        if (lane == 0) out[(long)row * NOUT + o] = s;
    }
}

extern "C" void kernel_launch(void* const* d_in, const int* in_sizes, int n_in,
                              void* d_out, int out_size, void* d_ws, size_t ws_size,
                              hipStream_t stream)
{
    const float* x        = (const float*)d_in[0];
    const float* pos      = (const float*)d_in[1];
    const float* in_w     = (const float*)d_in[2];
    const float* feats    = (const float*)d_in[3];
    const float* out_w    = (const float*)d_in[4];
    const float* biases   = (const float*)d_in[5];
    float* out = (float*)d_out;

    char* ws = (char*)d_ws;
    unsigned short* iw_bf  = (unsigned short*)(ws);                  //  3,145,728 B
    unsigned short* connw  = (unsigned short*)(ws + 3145728);        //    524,288 B
    unsigned short* act_a  = (unsigned short*)(ws + 3670016);        //  8,388,608 B
    unsigned short* act_b  = (unsigned short*)(ws + 12058624);       //  8,388,608 B
    float* feat_norm = (float*)(ws + 20447232);                      //    131,072 B
    float* pos_c     = (float*)(ws + 20578304);                      //      8,192 B
    float* inw       = (float*)(ws + 20586496);                      //      2,048 B
    float* biasp     = (float*)(ws + 20588544);                      //      2,048 B
    float* wout      = (float*)(ws + 20590592);                      //     20,480 B
    float* partials  = (float*)(ws + 20611072);                      // 67,108,864 B (4 x 16 MB)

    prep1<<<1, 512, 0, stream>>>(pos, feats, out_w, biases, feat_norm, pos_c, inw, biasp, wout);
    prep2<<<512, 128, 0, stream>>>(pos_c, feat_norm, connw);
    cast_pad<<<512, 256, 0, stream>>>(in_w, iw_bf, 393216L, 384000L);

    gemm1s<<<2048, 256, 0, stream>>>(x, iw_bf, partials);
    reduce_ep<<<2048, 256, 0, stream>>>(partials, inw, biasp, act_a);

    gemm2_pipe<<<512, 256, 0, stream>>>(act_a, connw, act_b, act_a);
    gemm2_pipe<<<512, 256, 0, stream>>>(act_b, connw, act_a, act_b);
    gemm2_pipe<<<512, 256, 0, stream>>>(act_a, connw, act_b, act_a);

    out_gemm<<<NBATCH/4, 256, 0, stream>>>(act_b, wout, out);
}

// Round 14
// 129.106 us; speedup vs baseline: 1.0753x; 1.0753x over previous
//
#include <hip/hip_runtime.h>
#include <stdint.h>

#define N_REAL 500
#define NPAD   512
#define K_IN   3072
#define NBATCH 8192
#define NOUT   10
#define RADIUS 20.0f
#define VOLF   100.0f

typedef __attribute__((ext_vector_type(8))) __bf16 bf16x8;
typedef __attribute__((ext_vector_type(4))) float  f32x4;
typedef __attribute__((ext_vector_type(4))) unsigned short us4;

__device__ __forceinline__ unsigned short f2bf(float f) {
    unsigned int u = __float_as_uint(f);
    u += 0x7FFFu + ((u >> 16) & 1u);           // round-to-nearest-even
    return (unsigned short)(u >> 16);
}
__device__ __forceinline__ float bf2f(unsigned short h) {
    return __uint_as_float(((unsigned int)h) << 16);
}
// 8x f32 -> bf16x8 via HW packed cvt (RNE; bitwise == f2bf)
__device__ __forceinline__ bf16x8 cvt8(float4 lo, float4 hi) {
    union { unsigned int u[4]; bf16x8 v; } x;
    asm("v_cvt_pk_bf16_f32 %0, %1, %2" : "=v"(x.u[0]) : "v"(lo.x), "v"(lo.y));
    asm("v_cvt_pk_bf16_f32 %0, %1, %2" : "=v"(x.u[1]) : "v"(lo.z), "v"(lo.w));
    asm("v_cvt_pk_bf16_f32 %0, %1, %2" : "=v"(x.u[2]) : "v"(hi.x), "v"(hi.y));
    asm("v_cvt_pk_bf16_f32 %0, %1, %2" : "=v"(x.u[3]) : "v"(hi.z), "v"(hi.w));
    return x.v;
}

#define GLOBAL_AS __attribute__((address_space(1)))
#define LDS_AS    __attribute__((address_space(3)))
__device__ __forceinline__ void glds16(const void* g, void* l) {
    __builtin_amdgcn_global_load_lds((const GLOBAL_AS void*)g, (LDS_AS void*)l, 16, 0, 0);
}

// ---------------- prep1 ----------------
__global__ void prep1(const float* __restrict__ positions,
                      const float* __restrict__ features,
                      const float* __restrict__ out_w,
                      const float* __restrict__ biases,
                      float* __restrict__ feat_norm,   // [512][64]
                      float* __restrict__ pos_c,       // [512][4]
                      float* __restrict__ inw,         // [512]
                      float* __restrict__ biasp,       // [512]
                      float* __restrict__ wout)        // [512][10]
{
    int n = threadIdx.x;  // 512 threads, 1 block
    float e_in = 0.f, e_out = 0.f;
    float px = 0.f, py = 0.f, pz = 0.f;
    if (n < N_REAL) {
        px = fminf(fmaxf(positions[n*3+0], 0.1f), VOLF - 0.1f);
        py = fminf(fmaxf(positions[n*3+1], 0.1f), VOLF - 0.1f);
        pz = fminf(fmaxf(positions[n*3+2], 0.1f), VOLF - 0.1f);
        float xn = px / VOLF;
        e_in  = expf(-2.f * xn);
        e_out = expf(2.f * (xn - 1.f));
        float ss = 0.f;
        for (int f = 0; f < 64; ++f) { float v = features[n*64+f]; ss += v*v; }
        float nm = fmaxf(sqrtf(ss), 1e-6f);
        for (int f = 0; f < 64; ++f) feat_norm[n*64+f] = features[n*64+f] / nm;
    } else {
        for (int f = 0; f < 64; ++f) feat_norm[n*64+f] = 0.f;
    }
    pos_c[n*4+0] = px; pos_c[n*4+1] = py; pos_c[n*4+2] = pz; pos_c[n*4+3] = 0.f;

    __shared__ float s_in[512], s_out[512];
    s_in[n] = e_in; s_out[n] = e_out;
    __syncthreads();
    for (int s = 256; s > 0; s >>= 1) {
        if (n < s) { s_in[n] += s_in[n+s]; s_out[n] += s_out[n+s]; }
        __syncthreads();
    }
    float sum_in  = s_in[0]  + 1e-6f;
    float sum_out = s_out[0] + 1e-6f;

    inw[n]   = (n < N_REAL) ? (e_in / sum_in) : 0.f;
    biasp[n] = (n < N_REAL) ? biases[n] : 0.f;
    float wo = (n < N_REAL) ? (e_out / sum_out) : 0.f;
    for (int o = 0; o < NOUT; ++o)
        wout[n*NOUT + o] = (n < N_REAL) ? out_w[n*NOUT + o] * wo : 0.f;
}

// ---------------- prep2 ----------------
__global__ void prep2(const float* __restrict__ pos_c,
                      const float* __restrict__ feat_norm,
                      unsigned short* __restrict__ conn_w)   // [512][512] bf16
{
    int i = blockIdx.x;   // 512
    int t = threadIdx.x;  // 128
    __shared__ float fi[64];
    __shared__ float spos[4];
    __shared__ float red[128];
    if (t < 64) fi[t] = feat_norm[i*64 + t];
    if (t < 4)  spos[t] = pos_c[i*4 + t];
    __syncthreads();

    float w[4];
    float part = 0.f;
    for (int jj = 0; jj < 4; ++jj) {
        int j = t + jj*128;
        float val = 0.f;
        if (i < N_REAL && j < N_REAL) {
            float dx = spos[0] - pos_c[j*4+0];
            float dy = spos[1] - pos_c[j*4+1];
            float dz = spos[2] - pos_c[j*4+2];
            float sq = dx*dx + dy*dy + dz*dz;
            if (sq > 0.f) {
                float dist = sqrtf(sq);
                if (dist < RADIUS) {
                    float att = expf(-dist / RADIUS);
                    float sim = 0.f;
                    const float4* fj = (const float4*)(feat_norm + j*64);
                    const float4* fi4 = (const float4*)fi;
                    #pragma unroll
                    for (int f = 0; f < 16; ++f) {
                        float4 a = fi4[f]; float4 b = fj[f];
                        sim += a.x*b.x + a.y*b.y + a.z*b.z + a.w*b.w;
                    }
                    sim = fminf(fmaxf(sim, -1.f), 1.f);
                    val = att * (0.5f + 0.5f*sim);
                }
            }
        }
        w[jj] = val; part += val;
    }
    red[t] = part;
    __syncthreads();
    for (int s = 64; s > 0; s >>= 1) {
        if (t < s) red[t] += red[t+s];
        __syncthreads();
    }
    float inv = 1.f / (red[0] + 1e-6f);
    for (int jj = 0; jj < 4; ++jj)
        conn_w[(long)i*NPAD + t + jj*128] = f2bf(w[jj] * inv);
}

// ---------------- cast/pad f32 -> bf16 ----------------
__global__ void cast_pad(const float* __restrict__ src, unsigned short* __restrict__ dst,
                         long total_q, long src_q)
{
    long i = (long)blockIdx.x * blockDim.x + threadIdx.x;
    long stride = (long)gridDim.x * blockDim.x;
    for (; i < total_q; i += stride) {
        us4 o;
        if (i < src_q) {
            float4 v = ((const float4*)src)[i];
            o[0] = f2bf(v.x); o[1] = f2bf(v.y); o[2] = f2bf(v.z); o[3] = f2bf(v.w);
        } else {
            o[0] = 0; o[1] = 0; o[2] = 0; o[3] = 0;
        }
        ((us4*)dst)[i] = o;
    }
}

// gemm1 block map: 256 blocks = 128 m-panels x 2 n-halves, XCD-grouped.
__device__ __forceinline__ void block_map_g1(int b, int& m0, int& n0) {
    int xcd = b & 7, loc = b >> 3;          // loc 0..31
    m0 = (xcd*16 + (loc >> 1)) * 64;
    n0 = (loc & 1) * 256;
}
// gemm2 block map: 512 blocks = 128 m-panels x 4 n-quarters.
__device__ __forceinline__ void block_map_g2(int b, int& m0, int& n0) {
    int xcd = b & 7, loc = b >> 3;          // loc 0..63
    m0 = (xcd*16 + (loc >> 2)) * 64;
    n0 = (loc & 3) * 128;
}

// ======== GEMM1 (r7-proven, 80.5us): BM=64, BN=256, BK=64, 512 thr (2m x 4n waves).
// Depth-2, 3-buffer, ALL-glds16: X staged as f32 in LDS, cvt to bf16 post-ds_read.
// acc*inw + bias epilogue.
__global__ __launch_bounds__(512)
void gemm1_r7(const float* __restrict__ Xf,           // [8192][3072] f32
              const unsigned short* __restrict__ B,   // [512][3072] bf16
              unsigned short* __restrict__ Cbf,       // [8192][512] bf16
              const float* __restrict__ inw,
              const float* __restrict__ biasp)
{
    constexpr int ABUF = 16384;                        // 64 x 64 f32
    constexpr int BBUF = 32768;                        // 256 x 64 bf16
    __shared__ __align__(16) char lds[3*ABUF + 3*BBUF]; // 144 KB

    const int tid  = threadIdx.x;
    const int lane = tid & 63;
    const int wave = tid >> 6;
    int m0, n0; block_map_g1(blockIdx.x, m0, n0);
    const int wm = (wave >> 2) * 32;          // 2 m-waves
    const int wn = (wave & 3) * 64;           // 4 n-waves

    f32x4 acc[2][4];
    #pragma unroll
    for (int i = 0; i < 2; ++i)
        #pragma unroll
        for (int j = 0; j < 4; ++j)
            acc[i][j] = (f32x4){0.f,0.f,0.f,0.f};

    // B: 32 KB/tile -> 4 glds16/thread; 128 B rows, swz ((row&7)<<4)
    const char* gB[4]; int lBo[4];
    #pragma unroll
    for (int s = 0; s < 4; ++s) {
        int o = tid*16 + s*8192;
        int row = o >> 7, d = o & 127;
        gB[s] = (const char*)B + (long)(n0 + row) * (K_IN*2) + (d ^ ((row & 7) << 4));
        lBo[s] = o;
    }
    // A: f32 tile 64x64 = 16 KB -> 2 glds16/thread; 256 B rows,
    //    16B-slot swz (slot ^ (row&15))  [2-way bank alias = free]
    const char* gA[2]; int lAo[2];
    #pragma unroll
    for (int s = 0; s < 2; ++s) {
        int o = tid*16 + s*8192;
        int row = o >> 8, slot = (o >> 4) & 15;
        gA[s] = (const char*)Xf + (long)(m0 + row) * (K_IN*4) + ((slot ^ (row & 15)) << 4);
        lAo[s] = o;
    }

    const int NT = K_IN >> 6;   // 48

#define ISSUE_TILE(p)                                                          \
    do {                                                                       \
        glds16(gA[0], lds + (p)*ABUF + lAo[0]); gA[0] += 256;                  \
        glds16(gA[1], lds + (p)*ABUF + lAo[1]); gA[1] += 256;                  \
        glds16(gB[0], lds + 3*ABUF + (p)*BBUF + lBo[0]); gB[0] += 128;         \
        glds16(gB[1], lds + 3*ABUF + (p)*BBUF + lBo[1]); gB[1] += 128;         \
        glds16(gB[2], lds + 3*ABUF + (p)*BBUF + lBo[2]); gB[2] += 128;         \
        glds16(gB[3], lds + 3*ABUF + (p)*BBUF + lBo[3]); gB[3] += 128;         \
    } while (0)

    // prologue: tiles 0 and 1 in flight
    ISSUE_TILE(0);
    ISSUE_TILE(1);

    int cur = 0;
    for (int t = 0; t < NT; ++t) {
        int p2 = cur + 2; if (p2 >= 3) p2 -= 3;
        if (t + 2 < NT) {
            ISSUE_TILE(p2);
            // outstanding: t(6), t+1(6), t+2(6) -> drain tile t only
            asm volatile("s_waitcnt vmcnt(12)" ::: "memory");
        } else if (t + 1 < NT) {
            asm volatile("s_waitcnt vmcnt(6)" ::: "memory");
        } else {
            asm volatile("s_waitcnt vmcnt(0)" ::: "memory");
        }
        __builtin_amdgcn_s_barrier();   // tile t resident for all waves

        const char* Ab = lds + cur*ABUF;
        const char* Bb = lds + 3*ABUF + cur*BBUF;
        #pragma unroll
        for (int kk = 0; kk < 2; ++kk) {
            bf16x8 afr[2], bfr[4];
            #pragma unroll
            for (int i = 0; i < 2; ++i) {
                int r = wm + i*16 + (lane & 15);
                int s0 = kk*8 + (lane >> 4)*2;
                float4 lo = *(const float4*)(Ab + r*256 + (((s0    ) ^ (r & 15)) << 4));
                float4 hi = *(const float4*)(Ab + r*256 + (((s0 + 1) ^ (r & 15)) << 4));
                afr[i] = cvt8(lo, hi);
            }
            #pragma unroll
            for (int j = 0; j < 4; ++j) {
                int r = wn + j*16 + (lane & 15);
                bfr[j] = *(const bf16x8*)(Bb + r*128 + ((kk*64 + (lane >> 4)*16) ^ ((r & 7) << 4)));
            }
            #pragma unroll
            for (int i = 0; i < 2; ++i)
                #pragma unroll
                for (int j = 0; j < 4; ++j)
                    acc[i][j] = __builtin_amdgcn_mfma_f32_16x16x32_bf16(afr[i], bfr[j], acc[i][j], 0, 0, 0);
        }
        __builtin_amdgcn_s_barrier();   // reads done before buffer reuse
        cur = (cur == 2) ? 0 : cur + 1;
    }
#undef ISSUE_TILE

    // epilogue: acc * inw[n] + biasp[n]
    const int mbase = m0 + wm + (lane >> 4) * 4;
    const int nbase = n0 + wn + (lane & 15);
    #pragma unroll
    for (int j = 0; j < 4; ++j) {
        const int n = nbase + j*16;
        const float win = inw[n], bia = biasp[n];
        #pragma unroll
        for (int i = 0; i < 2; ++i)
            #pragma unroll
            for (int r = 0; r < 4; ++r) {
                const long m = mbase + i*16 + r;
                Cbf[m*NPAD + n] = f2bf(acc[i][j][r] * win + bia);
            }
    }
}

// ======== GEMM2 (r8/r12-proven): BM=64, BN=128, BK=64, 3-buffer ring, depth-2. ========
__global__ __launch_bounds__(256, 4)
void gemm2_pipe(const unsigned short* __restrict__ A,      // act [8192][512] bf16
                const unsigned short* __restrict__ B,      // connw [512][512] bf16
                unsigned short* __restrict__ Cbf,          // [8192][512] bf16
                const unsigned short* __restrict__ actOld) // == A
{
    constexpr int ABUF = 8192;    // 64 x 64 bf16
    constexpr int BBUF = 16384;   // 128 x 64 bf16
    __shared__ __align__(16) char lds[3*(ABUF+BBUF)];  // 72 KB
    char* const Abase = lds;
    char* const Bbase = lds + 3*ABUF;

    const int tid  = threadIdx.x;
    const int lane = tid & 63;
    const int wave = tid >> 6;
    int m0, n0; block_map_g2(blockIdx.x, m0, n0);
    const int wm = (wave >> 1) * 32;
    const int wn = (wave & 1) * 64;

    f32x4 acc[2][4];
    #pragma unroll
    for (int i = 0; i < 2; ++i)
        #pragma unroll
        for (int j = 0; j < 4; ++j)
            acc[i][j] = (f32x4){0.f,0.f,0.f,0.f};

    const char* gB[4]; int lBo[4];
    #pragma unroll
    for (int s = 0; s < 4; ++s) {
        int o = tid*16 + s*4096;
        int row = o >> 7, d = o & 127;
        gB[s] = (const char*)B + (long)(n0 + row) * (NPAD*2) + (d ^ ((row & 7) << 4));
        lBo[s] = o;
    }
    const char* gA1[2]; int lAo1[2];
    #pragma unroll
    for (int s = 0; s < 2; ++s) {
        int o = tid*16 + s*4096;
        int row = o >> 7, d = o & 127;
        gA1[s] = (const char*)A + (long)(m0 + row) * (NPAD*2) + (d ^ ((row & 7) << 4));
        lAo1[s] = o;
    }

    const int NT = NPAD >> 6;   // 8

    // prologue: tiles 0,1 in flight
    #pragma unroll
    for (int s = 0; s < 2; ++s) { glds16(gA1[s], Abase + 0*ABUF + lAo1[s]); gA1[s] += 128; }
    #pragma unroll
    for (int s = 0; s < 4; ++s) { glds16(gB[s], Bbase + 0*BBUF + lBo[s]); gB[s] += 128; }
    #pragma unroll
    for (int s = 0; s < 2; ++s) { glds16(gA1[s], Abase + 1*ABUF + lAo1[s]); gA1[s] += 128; }
    #pragma unroll
    for (int s = 0; s < 4; ++s) { glds16(gB[s], Bbase + 1*BBUF + lBo[s]); gB[s] += 128; }

    int cur = 0;
    for (int t = 0; t < NT; ++t) {
        int fb = cur + 2; if (fb >= 3) fb -= 3;
        const bool more2 = (t + 2 < NT);
        const bool more1 = (t + 1 < NT);
        if (more2) {
            #pragma unroll
            for (int s = 0; s < 2; ++s) { glds16(gA1[s], Abase + fb*ABUF + lAo1[s]); gA1[s] += 128; }
            #pragma unroll
            for (int s = 0; s < 4; ++s) { glds16(gB[s], Bbase + fb*BBUF + lBo[s]); gB[s] += 128; }
            asm volatile("s_waitcnt vmcnt(12)" ::: "memory");
        } else if (more1) {
            asm volatile("s_waitcnt vmcnt(6)" ::: "memory");
        } else {
            asm volatile("s_waitcnt vmcnt(0)" ::: "memory");
        }
        __builtin_amdgcn_s_barrier();

        const char* Ab = Abase + cur*ABUF;
        const char* Bb = Bbase + cur*BBUF;
        #pragma unroll
        for (int kk = 0; kk < 2; ++kk) {
            const int cb = kk*64 + (lane >> 4) * 16;
            bf16x8 afr[2], bfr[4];
            #pragma unroll
            for (int i = 0; i < 2; ++i) {
                int r = wm + i*16 + (lane & 15);
                afr[i] = *(const bf16x8*)(Ab + r*128 + (cb ^ ((r & 7) << 4)));
            }
            #pragma unroll
            for (int j = 0; j < 4; ++j) {
                int r = wn + j*16 + (lane & 15);
                bfr[j] = *(const bf16x8*)(Bb + r*128 + (cb ^ ((r & 7) << 4)));
            }
            #pragma unroll
            for (int i = 0; i < 2; ++i)
                #pragma unroll
                for (int j = 0; j < 4; ++j)
                    acc[i][j] = __builtin_amdgcn_mfma_f32_16x16x32_bf16(afr[i], bfr[j], acc[i][j], 0, 0, 0);
        }
        __builtin_amdgcn_s_barrier();
        cur = (cur == 2) ? 0 : cur + 1;
    }

    const int mbase = m0 + wm + (lane >> 4) * 4;
    const int nbase = n0 + wn + (lane & 15);
    #pragma unroll
    for (int j = 0; j < 4; ++j) {
        const int n = nbase + j*16;
        #pragma unroll
        for (int i = 0; i < 2; ++i)
            #pragma unroll
            for (int r = 0; r < 4; ++r) {
                const long m = mbase + i*16 + r;
                float old = bf2f(actOld[m*NPAD + n]);
                float vv = fminf(fmaxf(old + 0.5f * acc[i][j][r], 0.f), 50.f);
                Cbf[m*NPAD + n] = f2bf(vv);
            }
    }
}

// ---------------- final projection: out[8192][10] = act @ wout ----------------
__global__ __launch_bounds__(256)
void out_gemm(const unsigned short* __restrict__ act,  // [8192][512] bf16
              const float* __restrict__ wout,          // [512][10]
              float* __restrict__ out)                 // [8192][10]
{
    __shared__ float sw[NPAD * NOUT];
    const int tid = threadIdx.x;
    for (int i = tid; i < NPAD*NOUT; i += 256) sw[i] = wout[i];
    __syncthreads();

    const int lane = tid & 63;
    const int wv   = tid >> 6;
    const int row  = blockIdx.x * 4 + wv;

    const unsigned short* ap = act + (long)row * NPAD + lane * 8;
    us4 v0 = *(const us4*)(ap);
    us4 v1 = *(const us4*)(ap + 4);

    float p[NOUT];
    #pragma unroll
    for (int o = 0; o < NOUT; ++o) p[o] = 0.f;

    const int nb = lane * 8;
    #pragma unroll
    for (int e = 0; e < 8; ++e) {
        float a = bf2f(e < 4 ? v0[e] : v1[e-4]);
        const float* wr = &sw[(nb + e) * NOUT];
        #pragma unroll
        for (int o = 0; o < NOUT; ++o) p[o] += a * wr[o];
    }
    #pragma unroll
    for (int o = 0; o < NOUT; ++o) {
        float s = p[o];
        for (int d = 32; d > 0; d >>= 1) s += __shfl_down(s, d);
        if (lane == 0) out[(long)row * NOUT + o] = s;
    }
}

extern "C" void kernel_launch(void* const* d_in, const int* in_sizes, int n_in,
                              void* d_out, int out_size, void* d_ws, size_t ws_size,
                              hipStream_t stream)
{
    const float* x        = (const float*)d_in[0];
    const float* pos      = (const float*)d_in[1];
    const float* in_w     = (const float*)d_in[2];
    const float* feats    = (const float*)d_in[3];
    const float* out_w    = (const float*)d_in[4];
    const float* biases   = (const float*)d_in[5];
    float* out = (float*)d_out;

    char* ws = (char*)d_ws;
    unsigned short* iw_bf  = (unsigned short*)(ws);                  //  3,145,728 B
    unsigned short* connw  = (unsigned short*)(ws + 3145728);        //    524,288 B
    unsigned short* act_a  = (unsigned short*)(ws + 3670016);        //  8,388,608 B
    unsigned short* act_b  = (unsigned short*)(ws + 12058624);       //  8,388,608 B
    float* feat_norm = (float*)(ws + 20447232);                      //    131,072 B
    float* pos_c     = (float*)(ws + 20578304);                      //      8,192 B
    float* inw       = (float*)(ws + 20586496);                      //      2,048 B
    float* biasp     = (float*)(ws + 20588544);                      //      2,048 B
    float* wout      = (float*)(ws + 20590592);                      //     20,480 B

    prep1<<<1, 512, 0, stream>>>(pos, feats, out_w, biases, feat_norm, pos_c, inw, biasp, wout);
    prep2<<<512, 128, 0, stream>>>(pos_c, feat_norm, connw);
    cast_pad<<<512, 256, 0, stream>>>(in_w, iw_bf, 393216L, 384000L);

    gemm1_r7<<<256, 512, 0, stream>>>(x, iw_bf, act_a, inw, biasp);

    gemm2_pipe<<<512, 256, 0, stream>>>(act_a, connw, act_b, act_a);
    gemm2_pipe<<<512, 256, 0, stream>>>(act_b, connw, act_a, act_b);
    gemm2_pipe<<<512, 256, 0, stream>>>(act_a, connw, act_b, act_a);

    out_gemm<<<NBATCH/4, 256, 0, stream>>>(act_b, wout, out);
}

// Round 15
// 116.060 us; speedup vs baseline: 1.1961x; 1.1124x over previous
//
#include <hip/hip_runtime.h>
#include <stdint.h>

#define N_REAL 500
#define NPAD   512
#define K_IN   3072
#define NBATCH 8192
#define NOUT   10
#define RADIUS 20.0f
#define VOLF   100.0f

typedef __attribute__((ext_vector_type(8))) __bf16 bf16x8;
typedef __attribute__((ext_vector_type(4))) float  f32x4;
typedef __attribute__((ext_vector_type(4))) unsigned short us4;

__device__ __forceinline__ unsigned short f2bf(float f) {
    unsigned int u = __float_as_uint(f);
    u += 0x7FFFu + ((u >> 16) & 1u);           // round-to-nearest-even
    return (unsigned short)(u >> 16);
}
__device__ __forceinline__ float bf2f(unsigned short h) {
    return __uint_as_float(((unsigned int)h) << 16);
}
// HW packed f32->bf16 (RNE), 2 insts per float4
__device__ __forceinline__ uint2 cvt_pk4(float4 v) {
    uint2 r;
    asm("v_cvt_pk_bf16_f32 %0, %1, %2" : "=v"(r.x) : "v"(v.x), "v"(v.y));
    asm("v_cvt_pk_bf16_f32 %0, %1, %2" : "=v"(r.y) : "v"(v.z), "v"(v.w));
    return r;
}

#define GLOBAL_AS __attribute__((address_space(1)))
#define LDS_AS    __attribute__((address_space(3)))
__device__ __forceinline__ void glds16(const void* g, void* l) {
    __builtin_amdgcn_global_load_lds((const GLOBAL_AS void*)g, (LDS_AS void*)l, 16, 0, 0);
}

// ---------------- prep1 ----------------
__global__ void prep1(const float* __restrict__ positions,
                      const float* __restrict__ features,
                      const float* __restrict__ out_w,
                      const float* __restrict__ biases,
                      float* __restrict__ feat_norm,   // [512][64]
                      float* __restrict__ pos_c,       // [512][4]
                      float* __restrict__ inw,         // [512]
                      float* __restrict__ biasp,       // [512]
                      float* __restrict__ wout)        // [512][10]
{
    int n = threadIdx.x;  // 512 threads, 1 block
    float e_in = 0.f, e_out = 0.f;
    float px = 0.f, py = 0.f, pz = 0.f;
    if (n < N_REAL) {
        px = fminf(fmaxf(positions[n*3+0], 0.1f), VOLF - 0.1f);
        py = fminf(fmaxf(positions[n*3+1], 0.1f), VOLF - 0.1f);
        pz = fminf(fmaxf(positions[n*3+2], 0.1f), VOLF - 0.1f);
        float xn = px / VOLF;
        e_in  = expf(-2.f * xn);
        e_out = expf(2.f * (xn - 1.f));
        float ss = 0.f;
        for (int f = 0; f < 64; ++f) { float v = features[n*64+f]; ss += v*v; }
        float nm = fmaxf(sqrtf(ss), 1e-6f);
        for (int f = 0; f < 64; ++f) feat_norm[n*64+f] = features[n*64+f] / nm;
    } else {
        for (int f = 0; f < 64; ++f) feat_norm[n*64+f] = 0.f;
    }
    pos_c[n*4+0] = px; pos_c[n*4+1] = py; pos_c[n*4+2] = pz; pos_c[n*4+3] = 0.f;

    __shared__ float s_in[512], s_out[512];
    s_in[n] = e_in; s_out[n] = e_out;
    __syncthreads();
    for (int s = 256; s > 0; s >>= 1) {
        if (n < s) { s_in[n] += s_in[n+s]; s_out[n] += s_out[n+s]; }
        __syncthreads();
    }
    float sum_in  = s_in[0]  + 1e-6f;
    float sum_out = s_out[0] + 1e-6f;

    inw[n]   = (n < N_REAL) ? (e_in / sum_in) : 0.f;
    biasp[n] = (n < N_REAL) ? biases[n] : 0.f;
    float wo = (n < N_REAL) ? (e_out / sum_out) : 0.f;
    for (int o = 0; o < NOUT; ++o)
        wout[n*NOUT + o] = (n < N_REAL) ? out_w[n*NOUT + o] * wo : 0.f;
}

// ---------------- prep2 ----------------
__global__ void prep2(const float* __restrict__ pos_c,
                      const float* __restrict__ feat_norm,
                      unsigned short* __restrict__ conn_w)   // [512][512] bf16
{
    int i = blockIdx.x;   // 512
    int t = threadIdx.x;  // 128
    __shared__ float fi[64];
    __shared__ float spos[4];
    __shared__ float red[128];
    if (t < 64) fi[t] = feat_norm[i*64 + t];
    if (t < 4)  spos[t] = pos_c[i*4 + t];
    __syncthreads();

    float w[4];
    float part = 0.f;
    for (int jj = 0; jj < 4; ++jj) {
        int j = t + jj*128;
        float val = 0.f;
        if (i < N_REAL && j < N_REAL) {
            float dx = spos[0] - pos_c[j*4+0];
            float dy = spos[1] - pos_c[j*4+1];
            float dz = spos[2] - pos_c[j*4+2];
            float sq = dx*dx + dy*dy + dz*dz;
            if (sq > 0.f) {
                float dist = sqrtf(sq);
                if (dist < RADIUS) {
                    float att = expf(-dist / RADIUS);
                    float sim = 0.f;
                    const float4* fj = (const float4*)(feat_norm + j*64);
                    const float4* fi4 = (const float4*)fi;
                    #pragma unroll
                    for (int f = 0; f < 16; ++f) {
                        float4 a = fi4[f]; float4 b = fj[f];
                        sim += a.x*b.x + a.y*b.y + a.z*b.z + a.w*b.w;
                    }
                    sim = fminf(fmaxf(sim, -1.f), 1.f);
                    val = att * (0.5f + 0.5f*sim);
                }
            }
        }
        w[jj] = val; part += val;
    }
    red[t] = part;
    __syncthreads();
    for (int s = 64; s > 0; s >>= 1) {
        if (t < s) red[t] += red[t+s];
        __syncthreads();
    }
    float inv = 1.f / (red[0] + 1e-6f);
    for (int jj = 0; jj < 4; ++jj)
        conn_w[(long)i*NPAD + t + jj*128] = f2bf(w[jj] * inv);
}

// ---------------- cast/pad f32 -> bf16 ----------------
__global__ void cast_pad(const float* __restrict__ src, unsigned short* __restrict__ dst,
                         long total_q, long src_q)
{
    long i = (long)blockIdx.x * blockDim.x + threadIdx.x;
    long stride = (long)gridDim.x * blockDim.x;
    for (; i < total_q; i += stride) {
        us4 o;
        if (i < src_q) {
            float4 v = ((const float4*)src)[i];
            o[0] = f2bf(v.x); o[1] = f2bf(v.y); o[2] = f2bf(v.z); o[3] = f2bf(v.w);
        } else {
            o[0] = 0; o[1] = 0; o[2] = 0; o[3] = 0;
        }
        ((us4*)dst)[i] = o;
    }
}

// Block map: 512 blocks = 128 m-panels x 4 n-quarters, XCD-grouped.
__device__ __forceinline__ void block_map_g2(int b, int& m0, int& n0) {
    int xcd = b & 7, loc = b >> 3;          // loc 0..63
    m0 = (xcd*16 + (loc >> 2)) * 64;
    n0 = (loc & 3) * 128;
}

// ======== GEMM1 strict (r12's session-best gemm1 dispatch, unsplit): ========
// BM=64, BN=128, BK=64, 256 thr (4 waves 2m x 2n), single 24 KB buffer,
// strict {stage -> drain -> compute} loop, NT=48, fused gate/bias epilogue.
__global__ __launch_bounds__(256)
void gemm1_strict(const float* __restrict__ X,            // [8192][3072] f32
                  const unsigned short* __restrict__ B,   // [512][3072] bf16
                  unsigned short* __restrict__ Cbf,       // [8192][512] bf16
                  const float* __restrict__ inw,
                  const float* __restrict__ biasp)
{
    __shared__ unsigned short As[64*64];    //  8 KiB, swizzled
    __shared__ unsigned short Bs[128*64];   // 16 KiB, swizzled

    const int tid  = threadIdx.x;
    const int lane = tid & 63;
    const int wave = tid >> 6;
    int m0, n0; block_map_g2(blockIdx.x, m0, n0);
    const int wm = (wave >> 1) * 32;
    const int wn = (wave & 1) * 64;

    f32x4 acc[2][4];
    #pragma unroll
    for (int i = 0; i < 2; ++i)
        #pragma unroll
        for (int j = 0; j < 4; ++j)
            acc[i][j] = (f32x4){0.f,0.f,0.f,0.f};

    // A reg-staging: 64 rows x 16 float4 = 1024 f4, 4 per thread
    const float4* gA[4]; int lAo[4];
    #pragma unroll
    for (int s = 0; s < 4; ++s) {
        int f = tid + s*256;
        int row = f >> 4, c4 = f & 15;
        gA[s] = (const float4*)(X + (long)(m0 + row) * K_IN) + c4;
        lAo[s] = row*128 + ((c4*8) ^ ((row & 7) << 4));
    }
    // B: 16 KB = 4 glds16/thread, pre-swizzled global source
    const char* gB[4]; char* lB[4];
    #pragma unroll
    for (int s = 0; s < 4; ++s) {
        int o = tid*16 + s*4096;
        int row = o >> 7, d = o & 127;
        gB[s] = (const char*)B + (long)(n0 + row) * (K_IN*2) + (d ^ ((row & 7) << 4));
        lB[s] = (char*)Bs + o;
    }

    for (int t = 0; t < 48; ++t) {
        __syncthreads();
        #pragma unroll
        for (int s = 0; s < 4; ++s) { glds16(gB[s], lB[s]); gB[s] += 128; }
        float4 v[4];
        #pragma unroll
        for (int s = 0; s < 4; ++s) { v[s] = gA[s][0]; gA[s] += 16; }
        #pragma unroll
        for (int s = 0; s < 4; ++s)
            *(uint2*)((char*)As + lAo[s]) = cvt_pk4(v[s]);
        asm volatile("s_waitcnt vmcnt(0) lgkmcnt(0)" ::: "memory");
        __syncthreads();

        #pragma unroll
        for (int kk = 0; kk < 2; ++kk) {
            const int cb = kk*64 + (lane >> 4) * 16;
            bf16x8 afr[2], bfr[4];
            #pragma unroll
            for (int i = 0; i < 2; ++i) {
                int r = wm + i*16 + (lane & 15);
                afr[i] = *(const bf16x8*)((const char*)As + r*128 + (cb ^ ((r & 7) << 4)));
            }
            #pragma unroll
            for (int j = 0; j < 4; ++j) {
                int r = wn + j*16 + (lane & 15);
                bfr[j] = *(const bf16x8*)((const char*)Bs + r*128 + (cb ^ ((r & 7) << 4)));
            }
            #pragma unroll
            for (int i = 0; i < 2; ++i)
                #pragma unroll
                for (int j = 0; j < 4; ++j)
                    acc[i][j] = __builtin_amdgcn_mfma_f32_16x16x32_bf16(afr[i], bfr[j], acc[i][j], 0, 0, 0);
        }
    }

    // fused epilogue: acc * inw[n] + biasp[n] -> bf16 act
    const int mbase = m0 + wm + (lane >> 4) * 4;
    const int nbase = n0 + wn + (lane & 15);
    #pragma unroll
    for (int j = 0; j < 4; ++j) {
        const int n = nbase + j*16;
        const float win = inw[n], bia = biasp[n];
        #pragma unroll
        for (int i = 0; i < 2; ++i)
            #pragma unroll
            for (int r = 0; r < 4; ++r) {
                const long m = mbase + i*16 + r;
                Cbf[m*NPAD + n] = f2bf(acc[i][j][r] * win + bia);
            }
    }
}

// ======== GEMM2 (r8/r12-proven): BM=64, BN=128, BK=64, 3-buffer ring, depth-2. ========
__global__ __launch_bounds__(256, 4)
void gemm2_pipe(const unsigned short* __restrict__ A,      // act [8192][512] bf16
                const unsigned short* __restrict__ B,      // connw [512][512] bf16
                unsigned short* __restrict__ Cbf,          // [8192][512] bf16
                const unsigned short* __restrict__ actOld) // == A
{
    constexpr int ABUF = 8192;    // 64 x 64 bf16
    constexpr int BBUF = 16384;   // 128 x 64 bf16
    __shared__ __align__(16) char lds[3*(ABUF+BBUF)];  // 72 KB
    char* const Abase = lds;
    char* const Bbase = lds + 3*ABUF;

    const int tid  = threadIdx.x;
    const int lane = tid & 63;
    const int wave = tid >> 6;
    int m0, n0; block_map_g2(blockIdx.x, m0, n0);
    const int wm = (wave >> 1) * 32;
    const int wn = (wave & 1) * 64;

    f32x4 acc[2][4];
    #pragma unroll
    for (int i = 0; i < 2; ++i)
        #pragma unroll
        for (int j = 0; j < 4; ++j)
            acc[i][j] = (f32x4){0.f,0.f,0.f,0.f};

    const char* gB[4]; int lBo[4];
    #pragma unroll
    for (int s = 0; s < 4; ++s) {
        int o = tid*16 + s*4096;
        int row = o >> 7, d = o & 127;
        gB[s] = (const char*)B + (long)(n0 + row) * (NPAD*2) + (d ^ ((row & 7) << 4));
        lBo[s] = o;
    }
    const char* gA1[2]; int lAo1[2];
    #pragma unroll
    for (int s = 0; s < 2; ++s) {
        int o = tid*16 + s*4096;
        int row = o >> 7, d = o & 127;
        gA1[s] = (const char*)A + (long)(m0 + row) * (NPAD*2) + (d ^ ((row & 7) << 4));
        lAo1[s] = o;
    }

    const int NT = NPAD >> 6;   // 8

    // prologue: tiles 0,1 in flight
    #pragma unroll
    for (int s = 0; s < 2; ++s) { glds16(gA1[s], Abase + 0*ABUF + lAo1[s]); gA1[s] += 128; }
    #pragma unroll
    for (int s = 0; s < 4; ++s) { glds16(gB[s], Bbase + 0*BBUF + lBo[s]); gB[s] += 128; }
    #pragma unroll
    for (int s = 0; s < 2; ++s) { glds16(gA1[s], Abase + 1*ABUF + lAo1[s]); gA1[s] += 128; }
    #pragma unroll
    for (int s = 0; s < 4; ++s) { glds16(gB[s], Bbase + 1*BBUF + lBo[s]); gB[s] += 128; }

    int cur = 0;
    for (int t = 0; t < NT; ++t) {
        int fb = cur + 2; if (fb >= 3) fb -= 3;
        const bool more2 = (t + 2 < NT);
        const bool more1 = (t + 1 < NT);
        if (more2) {
            #pragma unroll
            for (int s = 0; s < 2; ++s) { glds16(gA1[s], Abase + fb*ABUF + lAo1[s]); gA1[s] += 128; }
            #pragma unroll
            for (int s = 0; s < 4; ++s) { glds16(gB[s], Bbase + fb*BBUF + lBo[s]); gB[s] += 128; }
            asm volatile("s_waitcnt vmcnt(12)" ::: "memory");
        } else if (more1) {
            asm volatile("s_waitcnt vmcnt(6)" ::: "memory");
        } else {
            asm volatile("s_waitcnt vmcnt(0)" ::: "memory");
        }
        __builtin_amdgcn_s_barrier();

        const char* Ab = Abase + cur*ABUF;
        const char* Bb = Bbase + cur*BBUF;
        #pragma unroll
        for (int kk = 0; kk < 2; ++kk) {
            const int cb = kk*64 + (lane >> 4) * 16;
            bf16x8 afr[2], bfr[4];
            #pragma unroll
            for (int i = 0; i < 2; ++i) {
                int r = wm + i*16 + (lane & 15);
                afr[i] = *(const bf16x8*)(Ab + r*128 + (cb ^ ((r & 7) << 4)));
            }
            #pragma unroll
            for (int j = 0; j < 4; ++j) {
                int r = wn + j*16 + (lane & 15);
                bfr[j] = *(const bf16x8*)(Bb + r*128 + (cb ^ ((r & 7) << 4)));
            }
            #pragma unroll
            for (int i = 0; i < 2; ++i)
                #pragma unroll
                for (int j = 0; j < 4; ++j)
                    acc[i][j] = __builtin_amdgcn_mfma_f32_16x16x32_bf16(afr[i], bfr[j], acc[i][j], 0, 0, 0);
        }
        __builtin_amdgcn_s_barrier();
        cur = (cur == 2) ? 0 : cur + 1;
    }

    const int mbase = m0 + wm + (lane >> 4) * 4;
    const int nbase = n0 + wn + (lane & 15);
    #pragma unroll
    for (int j = 0; j < 4; ++j) {
        const int n = nbase + j*16;
        #pragma unroll
        for (int i = 0; i < 2; ++i)
            #pragma unroll
            for (int r = 0; r < 4; ++r) {
                const long m = mbase + i*16 + r;
                float old = bf2f(actOld[m*NPAD + n]);
                float vv = fminf(fmaxf(old + 0.5f * acc[i][j][r], 0.f), 50.f);
                Cbf[m*NPAD + n] = f2bf(vv);
            }
    }
}

// ---------------- final projection: out[8192][10] = act @ wout ----------------
__global__ __launch_bounds__(256)
void out_gemm(const unsigned short* __restrict__ act,  // [8192][512] bf16
              const float* __restrict__ wout,          // [512][10]
              float* __restrict__ out)                 // [8192][10]
{
    __shared__ float sw[NPAD * NOUT];
    const int tid = threadIdx.x;
    for (int i = tid; i < NPAD*NOUT; i += 256) sw[i] = wout[i];
    __syncthreads();

    const int lane = tid & 63;
    const int wv   = tid >> 6;
    const int row  = blockIdx.x * 4 + wv;

    const unsigned short* ap = act + (long)row * NPAD + lane * 8;
    us4 v0 = *(const us4*)(ap);
    us4 v1 = *(const us4*)(ap + 4);

    float p[NOUT];
    #pragma unroll
    for (int o = 0; o < NOUT; ++o) p[o] = 0.f;

    const int nb = lane * 8;
    #pragma unroll
    for (int e = 0; e < 8; ++e) {
        float a = bf2f(e < 4 ? v0[e] : v1[e-4]);
        const float* wr = &sw[(nb + e) * NOUT];
        #pragma unroll
        for (int o = 0; o < NOUT; ++o) p[o] += a * wr[o];
    }
    #pragma unroll
    for (int o = 0; o < NOUT; ++o) {
        float s = p[o];
        for (int d = 32; d > 0; d >>= 1) s += __shfl_down(s, d);
        if (lane == 0) out[(long)row * NOUT + o] = s;
    }
}

extern "C" void kernel_launch(void* const* d_in, const int* in_sizes, int n_in,
                              void* d_out, int out_size, void* d_ws, size_t ws_size,
                              hipStream_t stream)
{
    const float* x        = (const float*)d_in[0];
    const float* pos      = (const float*)d_in[1];
    const float* in_w     = (const float*)d_in[2];
    const float* feats    = (const float*)d_in[3];
    const float* out_w    = (const float*)d_in[4];
    const float* biases   = (const float*)d_in[5];
    float* out = (float*)d_out;

    char* ws = (char*)d_ws;
    unsigned short* iw_bf  = (unsigned short*)(ws);                  //  3,145,728 B
    unsigned short* connw  = (unsigned short*)(ws + 3145728);        //    524,288 B
    unsigned short* act_a  = (unsigned short*)(ws + 3670016);        //  8,388,608 B
    unsigned short* act_b  = (unsigned short*)(ws + 12058624);       //  8,388,608 B
    float* feat_norm = (float*)(ws + 20447232);                      //    131,072 B
    float* pos_c     = (float*)(ws + 20578304);                      //      8,192 B
    float* inw       = (float*)(ws + 20586496);                      //      2,048 B
    float* biasp     = (float*)(ws + 20588544);                      //      2,048 B
    float* wout      = (float*)(ws + 20590592);                      //     20,480 B

    prep1<<<1, 512, 0, stream>>>(pos, feats, out_w, biases, feat_norm, pos_c, inw, biasp, wout);
    prep2<<<512, 128, 0, stream>>>(pos_c, feat_norm, connw);
    cast_pad<<<512, 256, 0, stream>>>(in_w, iw_bf, 393216L, 384000L);

    gemm1_strict<<<512, 256, 0, stream>>>(x, iw_bf, act_a, inw, biasp);

    gemm2_pipe<<<512, 256, 0, stream>>>(act_a, connw, act_b, act_a);
    gemm2_pipe<<<512, 256, 0, stream>>>(act_b, connw, act_a, act_b);
    gemm2_pipe<<<512, 256, 0, stream>>>(act_a, connw, act_b, act_a);

    out_gemm<<<NBATCH/4, 256, 0, stream>>>(act_b, wout, out);
}

// Round 16
// 110.722 us; speedup vs baseline: 1.2538x; 1.0482x over previous
//
#include <hip/hip_runtime.h>
#include <stdint.h>

#define N_REAL 500
#define NPAD   512
#define K_IN   3072
#define NBATCH 8192
#define NOUT   10
#define RADIUS 20.0f
#define VOLF   100.0f

typedef __attribute__((ext_vector_type(8))) __bf16 bf16x8;
typedef __attribute__((ext_vector_type(4))) float  f32x4;
typedef __attribute__((ext_vector_type(4))) unsigned short us4;

__device__ __forceinline__ unsigned short f2bf(float f) {
    unsigned int u = __float_as_uint(f);
    u += 0x7FFFu + ((u >> 16) & 1u);           // round-to-nearest-even
    return (unsigned short)(u >> 16);
}
__device__ __forceinline__ float bf2f(unsigned short h) {
    return __uint_as_float(((unsigned int)h) << 16);
}
// HW packed f32->bf16 (RNE), 2 insts per float4
__device__ __forceinline__ uint2 cvt_pk4(float4 v) {
    uint2 r;
    asm("v_cvt_pk_bf16_f32 %0, %1, %2" : "=v"(r.x) : "v"(v.x), "v"(v.y));
    asm("v_cvt_pk_bf16_f32 %0, %1, %2" : "=v"(r.y) : "v"(v.z), "v"(v.w));
    return r;
}

#define GLOBAL_AS __attribute__((address_space(1)))
#define LDS_AS    __attribute__((address_space(3)))
__device__ __forceinline__ void glds16(const void* g, void* l) {
    __builtin_amdgcn_global_load_lds((const GLOBAL_AS void*)g, (LDS_AS void*)l, 16, 0, 0);
}

// ---------------- prep1 + cast fused: block 0 = per-neuron prep; blocks 1.. = cast iw ----------------
__global__ void prep1_cast(const float* __restrict__ positions,
                           const float* __restrict__ features,
                           const float* __restrict__ out_w,
                           const float* __restrict__ biases,
                           const float* __restrict__ iw_src,      // in_w f32
                           float* __restrict__ feat_norm,   // [512][64]
                           float* __restrict__ pos_c,       // [512][4]
                           float* __restrict__ inw,         // [512]
                           float* __restrict__ biasp,       // [512]
                           float* __restrict__ wout,        // [512][10]
                           unsigned short* __restrict__ iw_bf)  // [512][3072] bf16
{
    __shared__ float s_in[512], s_out[512];
    if (blockIdx.x != 0) {
        // cast/pad in_w: 393216 quads total, 384000 real
        const long total_q = 393216L, src_q = 384000L;
        long i = (long)(blockIdx.x - 1) * 512 + threadIdx.x;
        const long stride = 512L * 512L;
        for (; i < total_q; i += stride) {
            us4 o;
            if (i < src_q) {
                float4 v = ((const float4*)iw_src)[i];
                o[0] = f2bf(v.x); o[1] = f2bf(v.y); o[2] = f2bf(v.z); o[3] = f2bf(v.w);
            } else {
                o[0] = 0; o[1] = 0; o[2] = 0; o[3] = 0;
            }
            ((us4*)iw_bf)[i] = o;
        }
        return;
    }

    int n = threadIdx.x;  // 512 threads
    float e_in = 0.f, e_out = 0.f;
    float px = 0.f, py = 0.f, pz = 0.f;
    if (n < N_REAL) {
        px = fminf(fmaxf(positions[n*3+0], 0.1f), VOLF - 0.1f);
        py = fminf(fmaxf(positions[n*3+1], 0.1f), VOLF - 0.1f);
        pz = fminf(fmaxf(positions[n*3+2], 0.1f), VOLF - 0.1f);
        float xn = px / VOLF;
        e_in  = expf(-2.f * xn);
        e_out = expf(2.f * (xn - 1.f));
        float ss = 0.f;
        for (int f = 0; f < 64; ++f) { float v = features[n*64+f]; ss += v*v; }
        float nm = fmaxf(sqrtf(ss), 1e-6f);
        for (int f = 0; f < 64; ++f) feat_norm[n*64+f] = features[n*64+f] / nm;
    } else {
        for (int f = 0; f < 64; ++f) feat_norm[n*64+f] = 0.f;
    }
    pos_c[n*4+0] = px; pos_c[n*4+1] = py; pos_c[n*4+2] = pz; pos_c[n*4+3] = 0.f;

    s_in[n] = e_in; s_out[n] = e_out;
    __syncthreads();
    for (int s = 256; s > 0; s >>= 1) {
        if (n < s) { s_in[n] += s_in[n+s]; s_out[n] += s_out[n+s]; }
        __syncthreads();
    }
    float sum_in  = s_in[0]  + 1e-6f;
    float sum_out = s_out[0] + 1e-6f;

    inw[n]   = (n < N_REAL) ? (e_in / sum_in) : 0.f;
    biasp[n] = (n < N_REAL) ? biases[n] : 0.f;
    float wo = (n < N_REAL) ? (e_out / sum_out) : 0.f;
    for (int o = 0; o < NOUT; ++o)
        wout[n*NOUT + o] = (n < N_REAL) ? out_w[n*NOUT + o] * wo : 0.f;
}

// ---------------- prep2 ----------------
__global__ void prep2(const float* __restrict__ pos_c,
                      const float* __restrict__ feat_norm,
                      unsigned short* __restrict__ conn_w)   // [512][512] bf16
{
    int i = blockIdx.x;   // 512
    int t = threadIdx.x;  // 128
    __shared__ float fi[64];
    __shared__ float spos[4];
    __shared__ float red[128];
    if (t < 64) fi[t] = feat_norm[i*64 + t];
    if (t < 4)  spos[t] = pos_c[i*4 + t];
    __syncthreads();

    float w[4];
    float part = 0.f;
    for (int jj = 0; jj < 4; ++jj) {
        int j = t + jj*128;
        float val = 0.f;
        if (i < N_REAL && j < N_REAL) {
            float dx = spos[0] - pos_c[j*4+0];
            float dy = spos[1] - pos_c[j*4+1];
            float dz = spos[2] - pos_c[j*4+2];
            float sq = dx*dx + dy*dy + dz*dz;
            if (sq > 0.f) {
                float dist = sqrtf(sq);
                if (dist < RADIUS) {
                    float att = expf(-dist / RADIUS);
                    float sim = 0.f;
                    const float4* fj = (const float4*)(feat_norm + j*64);
                    const float4* fi4 = (const float4*)fi;
                    #pragma unroll
                    for (int f = 0; f < 16; ++f) {
                        float4 a = fi4[f]; float4 b = fj[f];
                        sim += a.x*b.x + a.y*b.y + a.z*b.z + a.w*b.w;
                    }
                    sim = fminf(fmaxf(sim, -1.f), 1.f);
                    val = att * (0.5f + 0.5f*sim);
                }
            }
        }
        w[jj] = val; part += val;
    }
    red[t] = part;
    __syncthreads();
    for (int s = 64; s > 0; s >>= 1) {
        if (t < s) red[t] += red[t+s];
        __syncthreads();
    }
    float inv = 1.f / (red[0] + 1e-6f);
    for (int jj = 0; jj < 4; ++jj)
        conn_w[(long)i*NPAD + t + jj*128] = f2bf(w[jj] * inv);
}

// Block map: 512 blocks = 128 m-panels x 4 n-quarters, XCD-grouped.
__device__ __forceinline__ void block_map_g2(int b, int& m0, int& n0) {
    int xcd = b & 7, loc = b >> 3;          // loc 0..63
    m0 = (xcd*16 + (loc >> 2)) * 64;
    n0 = (loc & 3) * 128;
}

// ======== GEMM1 strict (r15-proven, ~82us): BM=64, BN=128, BK=64, 4 waves,
// single 24 KB buffer, strict loop, NT=48, fused gate/bias epilogue. UNCHANGED. ========
__global__ __launch_bounds__(256)
void gemm1_strict(const float* __restrict__ X,            // [8192][3072] f32
                  const unsigned short* __restrict__ B,   // [512][3072] bf16
                  unsigned short* __restrict__ Cbf,       // [8192][512] bf16
                  const float* __restrict__ inw,
                  const float* __restrict__ biasp)
{
    __shared__ unsigned short As[64*64];    //  8 KiB, swizzled
    __shared__ unsigned short Bs[128*64];   // 16 KiB, swizzled

    const int tid  = threadIdx.x;
    const int lane = tid & 63;
    const int wave = tid >> 6;
    int m0, n0; block_map_g2(blockIdx.x, m0, n0);
    const int wm = (wave >> 1) * 32;
    const int wn = (wave & 1) * 64;

    f32x4 acc[2][4];
    #pragma unroll
    for (int i = 0; i < 2; ++i)
        #pragma unroll
        for (int j = 0; j < 4; ++j)
            acc[i][j] = (f32x4){0.f,0.f,0.f,0.f};

    const float4* gA[4]; int lAo[4];
    #pragma unroll
    for (int s = 0; s < 4; ++s) {
        int f = tid + s*256;
        int row = f >> 4, c4 = f & 15;
        gA[s] = (const float4*)(X + (long)(m0 + row) * K_IN) + c4;
        lAo[s] = row*128 + ((c4*8) ^ ((row & 7) << 4));
    }
    const char* gB[4]; char* lB[4];
    #pragma unroll
    for (int s = 0; s < 4; ++s) {
        int o = tid*16 + s*4096;
        int row = o >> 7, d = o & 127;
        gB[s] = (const char*)B + (long)(n0 + row) * (K_IN*2) + (d ^ ((row & 7) << 4));
        lB[s] = (char*)Bs + o;
    }

    for (int t = 0; t < 48; ++t) {
        __syncthreads();
        #pragma unroll
        for (int s = 0; s < 4; ++s) { glds16(gB[s], lB[s]); gB[s] += 128; }
        float4 v[4];
        #pragma unroll
        for (int s = 0; s < 4; ++s) { v[s] = gA[s][0]; gA[s] += 16; }
        #pragma unroll
        for (int s = 0; s < 4; ++s)
            *(uint2*)((char*)As + lAo[s]) = cvt_pk4(v[s]);
        asm volatile("s_waitcnt vmcnt(0) lgkmcnt(0)" ::: "memory");
        __syncthreads();

        #pragma unroll
        for (int kk = 0; kk < 2; ++kk) {
            const int cb = kk*64 + (lane >> 4) * 16;
            bf16x8 afr[2], bfr[4];
            #pragma unroll
            for (int i = 0; i < 2; ++i) {
                int r = wm + i*16 + (lane & 15);
                afr[i] = *(const bf16x8*)((const char*)As + r*128 + (cb ^ ((r & 7) << 4)));
            }
            #pragma unroll
            for (int j = 0; j < 4; ++j) {
                int r = wn + j*16 + (lane & 15);
                bfr[j] = *(const bf16x8*)((const char*)Bs + r*128 + (cb ^ ((r & 7) << 4)));
            }
            #pragma unroll
            for (int i = 0; i < 2; ++i)
                #pragma unroll
                for (int j = 0; j < 4; ++j)
                    acc[i][j] = __builtin_amdgcn_mfma_f32_16x16x32_bf16(afr[i], bfr[j], acc[i][j], 0, 0, 0);
        }
    }

    const int mbase = m0 + wm + (lane >> 4) * 4;
    const int nbase = n0 + wn + (lane & 15);
    #pragma unroll
    for (int j = 0; j < 4; ++j) {
        const int n = nbase + j*16;
        const float win = inw[n], bia = biasp[n];
        #pragma unroll
        for (int i = 0; i < 2; ++i)
            #pragma unroll
            for (int r = 0; r < 4; ++r) {
                const long m = mbase + i*16 + r;
                Cbf[m*NPAD + n] = f2bf(acc[i][j][r] * win + bia);
            }
    }
}

// ======== GEMM2 (r8/r15-proven K-loop): 3-buffer ring, depth-2.
// FUSE_OUT=1: instead of writing act, compute per-n-quarter out-partials
// [4][8192][10] f32 via wout (staged into dead ring LDS) + shfl/LDS reduction.
template<int FUSE_OUT>
__global__ __launch_bounds__(256, 4)
void gemm2_pipe(const unsigned short* __restrict__ A,      // act [8192][512] bf16
                const unsigned short* __restrict__ B,      // connw [512][512] bf16
                unsigned short* __restrict__ Cbf,          // [8192][512] bf16 (unused if FUSE_OUT)
                const unsigned short* __restrict__ actOld, // == A
                const float* __restrict__ wout_g,          // [512][10] f32 (FUSE_OUT)
                float* __restrict__ qout)                  // [4][8192][10] f32 (FUSE_OUT)
{
    constexpr int ABUF = 8192;    // 64 x 64 bf16
    constexpr int BBUF = 16384;   // 128 x 64 bf16
    __shared__ __align__(16) char lds[3*(ABUF+BBUF)];  // 72 KB
    char* const Abase = lds;
    char* const Bbase = lds + 3*ABUF;

    const int tid  = threadIdx.x;
    const int lane = tid & 63;
    const int wave = tid >> 6;
    int m0, n0; block_map_g2(blockIdx.x, m0, n0);
    const int wm = (wave >> 1) * 32;
    const int wn = (wave & 1) * 64;

    f32x4 acc[2][4];
    #pragma unroll
    for (int i = 0; i < 2; ++i)
        #pragma unroll
        for (int j = 0; j < 4; ++j)
            acc[i][j] = (f32x4){0.f,0.f,0.f,0.f};

    const char* gB[4]; int lBo[4];
    #pragma unroll
    for (int s = 0; s < 4; ++s) {
        int o = tid*16 + s*4096;
        int row = o >> 7, d = o & 127;
        gB[s] = (const char*)B + (long)(n0 + row) * (NPAD*2) + (d ^ ((row & 7) << 4));
        lBo[s] = o;
    }
    const char* gA1[2]; int lAo1[2];
    #pragma unroll
    for (int s = 0; s < 2; ++s) {
        int o = tid*16 + s*4096;
        int row = o >> 7, d = o & 127;
        gA1[s] = (const char*)A + (long)(m0 + row) * (NPAD*2) + (d ^ ((row & 7) << 4));
        lAo1[s] = o;
    }

    const int NT = NPAD >> 6;   // 8

    #pragma unroll
    for (int s = 0; s < 2; ++s) { glds16(gA1[s], Abase + 0*ABUF + lAo1[s]); gA1[s] += 128; }
    #pragma unroll
    for (int s = 0; s < 4; ++s) { glds16(gB[s], Bbase + 0*BBUF + lBo[s]); gB[s] += 128; }
    #pragma unroll
    for (int s = 0; s < 2; ++s) { glds16(gA1[s], Abase + 1*ABUF + lAo1[s]); gA1[s] += 128; }
    #pragma unroll
    for (int s = 0; s < 4; ++s) { glds16(gB[s], Bbase + 1*BBUF + lBo[s]); gB[s] += 128; }

    int cur = 0;
    for (int t = 0; t < NT; ++t) {
        int fb = cur + 2; if (fb >= 3) fb -= 3;
        const bool more2 = (t + 2 < NT);
        const bool more1 = (t + 1 < NT);
        if (more2) {
            #pragma unroll
            for (int s = 0; s < 2; ++s) { glds16(gA1[s], Abase + fb*ABUF + lAo1[s]); gA1[s] += 128; }
            #pragma unroll
            for (int s = 0; s < 4; ++s) { glds16(gB[s], Bbase + fb*BBUF + lBo[s]); gB[s] += 128; }
            asm volatile("s_waitcnt vmcnt(12)" ::: "memory");
        } else if (more1) {
            asm volatile("s_waitcnt vmcnt(6)" ::: "memory");
        } else {
            asm volatile("s_waitcnt vmcnt(0)" ::: "memory");
        }
        __builtin_amdgcn_s_barrier();

        const char* Ab = Abase + cur*ABUF;
        const char* Bb = Bbase + cur*BBUF;
        #pragma unroll
        for (int kk = 0; kk < 2; ++kk) {
            const int cb = kk*64 + (lane >> 4) * 16;
            bf16x8 afr[2], bfr[4];
            #pragma unroll
            for (int i = 0; i < 2; ++i) {
                int r = wm + i*16 + (lane & 15);
                afr[i] = *(const bf16x8*)(Ab + r*128 + (cb ^ ((r & 7) << 4)));
            }
            #pragma unroll
            for (int j = 0; j < 4; ++j) {
                int r = wn + j*16 + (lane & 15);
                bfr[j] = *(const bf16x8*)(Bb + r*128 + (cb ^ ((r & 7) << 4)));
            }
            #pragma unroll
            for (int i = 0; i < 2; ++i)
                #pragma unroll
                for (int j = 0; j < 4; ++j)
                    acc[i][j] = __builtin_amdgcn_mfma_f32_16x16x32_bf16(afr[i], bfr[j], acc[i][j], 0, 0, 0);
        }
        __builtin_amdgcn_s_barrier();
        cur = (cur == 2) ? 0 : cur + 1;
    }

    const int mbase = m0 + wm + (lane >> 4) * 4;
    const int nbase = n0 + wn + (lane & 15);

    if (FUSE_OUT == 0) {
        #pragma unroll
        for (int j = 0; j < 4; ++j) {
            const int n = nbase + j*16;
            #pragma unroll
            for (int i = 0; i < 2; ++i)
                #pragma unroll
                for (int r = 0; r < 4; ++r) {
                    const long m = mbase + i*16 + r;
                    float old = bf2f(actOld[m*NPAD + n]);
                    float vv = fminf(fmaxf(old + 0.5f * acc[i][j][r], 0.f), 50.f);
                    Cbf[m*NPAD + n] = f2bf(vv);
                }
        }
    } else {
        // finalize act values in registers (overwrite acc)
        #pragma unroll
        for (int j = 0; j < 4; ++j) {
            const int n = nbase + j*16;
            #pragma unroll
            for (int i = 0; i < 2; ++i)
                #pragma unroll
                for (int r = 0; r < 4; ++r) {
                    const long m = mbase + i*16 + r;
                    float old = bf2f(actOld[m*NPAD + n]);
                    acc[i][j][r] = fminf(fmaxf(old + 0.5f * acc[i][j][r], 0.f), 50.f);
                }
        }
        // stage wout into dead ring LDS (last K-loop barrier already passed)
        float* swout = (float*)lds;                    // [512*10] = 20 KB
        float* xw    = (float*)(lds + 20480);          // [2][64][10] = 5 KB
        for (int e = tid; e < NPAD*NOUT; e += 256) swout[e] = wout_g[e];
        __builtin_amdgcn_s_barrier();

        const int rlocal = wm + (lane >> 4) * 4;       // thread's base row in block
        #pragma unroll 1
        for (int o = 0; o < NOUT; ++o) {
            float po[8];
            #pragma unroll
            for (int i = 0; i < 2; ++i)
                #pragma unroll
                for (int r = 0; r < 4; ++r) {
                    float s = 0.f;
                    #pragma unroll
                    for (int j = 0; j < 4; ++j)
                        s += acc[i][j][r] * swout[(nbase + j*16)*NOUT + o];
                    po[i*4+r] = s;
                }
            // reduce over the 16 lanes (lane&15) sharing these rows
            #pragma unroll
            for (int d = 1; d < 16; d <<= 1)
                #pragma unroll
                for (int p = 0; p < 8; ++p)
                    po[p] += __shfl_xor(po[p], d);
            if ((lane & 15) == 0) {
                #pragma unroll
                for (int i = 0; i < 2; ++i)
                    #pragma unroll
                    for (int r = 0; r < 4; ++r)
                        xw[(wave & 1)*640 + (rlocal + i*16 + r)*NOUT + o] = po[i*4+r];
            }
        }
        __builtin_amdgcn_s_barrier();
        const int q = n0 >> 7;
        for (int e = tid; e < 64*NOUT; e += 256) {
            int row = e / NOUT, o = e % NOUT;
            float val = xw[row*NOUT + o] + xw[640 + row*NOUT + o];
            qout[(long)q * (NBATCH*NOUT) + (long)(m0 + row)*NOUT + o] = val;
        }
    }
}

// ---- combine 4 n-quarter partials (fixed order) -> out ----
__global__ __launch_bounds__(256)
void out_combine(const float* __restrict__ qout, float* __restrict__ out)
{
    const int TOT = NBATCH * NOUT;   // 81920
    int i = blockIdx.x * 256 + threadIdx.x;
    if (i < TOT)
        out[i] = ((qout[i] + qout[TOT + i]) + qout[2*TOT + i]) + qout[3*TOT + i];
}

extern "C" void kernel_launch(void* const* d_in, const int* in_sizes, int n_in,
                              void* d_out, int out_size, void* d_ws, size_t ws_size,
                              hipStream_t stream)
{
    const float* x        = (const float*)d_in[0];
    const float* pos      = (const float*)d_in[1];
    const float* in_w     = (const float*)d_in[2];
    const float* feats    = (const float*)d_in[3];
    const float* out_w    = (const float*)d_in[4];
    const float* biases   = (const float*)d_in[5];
    float* out = (float*)d_out;

    char* ws = (char*)d_ws;
    unsigned short* iw_bf  = (unsigned short*)(ws);                  //  3,145,728 B
    unsigned short* connw  = (unsigned short*)(ws + 3145728);        //    524,288 B
    unsigned short* act_a  = (unsigned short*)(ws + 3670016);        //  8,388,608 B
    unsigned short* act_b  = (unsigned short*)(ws + 12058624);       //  8,388,608 B
    float* feat_norm = (float*)(ws + 20447232);                      //    131,072 B
    float* pos_c     = (float*)(ws + 20578304);                      //      8,192 B
    float* inw       = (float*)(ws + 20586496);                      //      2,048 B
    float* biasp     = (float*)(ws + 20588544);                      //      2,048 B
    float* wout      = (float*)(ws + 20590592);                      //     20,480 B
    float* qout      = (float*)(ws + 20611072);                      //  1,310,720 B

    prep1_cast<<<513, 512, 0, stream>>>(pos, feats, out_w, biases, in_w,
                                        feat_norm, pos_c, inw, biasp, wout, iw_bf);
    prep2<<<512, 128, 0, stream>>>(pos_c, feat_norm, connw);

    gemm1_strict<<<512, 256, 0, stream>>>(x, iw_bf, act_a, inw, biasp);

    gemm2_pipe<0><<<512, 256, 0, stream>>>(act_a, connw, act_b, act_a, nullptr, nullptr);
    gemm2_pipe<0><<<512, 256, 0, stream>>>(act_b, connw, act_a, act_b, nullptr, nullptr);
    gemm2_pipe<1><<<512, 256, 0, stream>>>(act_a, connw, nullptr, act_a, wout, qout);

    out_combine<<<(NBATCH*NOUT + 255)/256, 256, 0, stream>>>(qout, out);
}